// Round 9
// baseline (321.300 us; speedup 1.0000x reference)
//
#include <hip/hip_runtime.h>
#include <hip/hip_bf16.h>

// GCN encoder: h = relu(Agg(h @ W)) x3 after input linear.
// N=20000 nodes, E=640000 edges, H=128.
// R1->R2: CSR pull-agg replaced atomics (3330->367us).
// R2->R3: bigger GEMM tiles (367->331us).
// R3->R4: parallel scan; 128-row GEMM blocks (331->274us).
// R4->R5: global-broadcast GEMM -> latency regression (355us).
// R5->R6: LDS-broadcast GEMM (282us).
// R6->R7: GEMMs on matrix pipe via 3-term bf16 split (245us).
// R7->R8: 4-slice fp32 agg -> REGRESSION (260us): slicing cut per-wave
//         bytes-in-flight 4KB->1KB and quadrupled csr re-reads.
// R8->R9: bf16 gather payload (163MB/layer), 2 slices x 64 cols
//         (2.5MB < 4MB XCD L2, slice=blockIdx&1), 16 edges in flight
//         per wave (8 loads x 256B), scalar index block + 8/4/2/1 tails;
//         mgemm waves halved to 16x64 (2500 waves, 2x TLP).
// ws layout: [dis: N f][off: N i][csr: E i][hh: N*128 bf16][hl: N*128 bf16]
//            [xwb: 2 slices x N x 64 bf16]

#define HDIM 128
#define SCAN_TILE 1024

typedef __attribute__((ext_vector_type(8))) short s8v;
typedef __attribute__((ext_vector_type(4))) float f4v;

__device__ __forceinline__ ushort f2bf(float f) {
    uint u = __float_as_uint(f);
    u += 0x7FFFu + ((u >> 16) & 1u);      // round-to-nearest-even
    return (ushort)(u >> 16);
}
__device__ __forceinline__ float bf2f(ushort h) {
    return __uint_as_float(((uint)h) << 16);
}

__global__ __launch_bounds__(256) void k_zero(int* __restrict__ off, int N) {
    int i = blockIdx.x * 256 + threadIdx.x;
    if (i < N) off[i] = 0;
}

__global__ __launch_bounds__(256) void k_count(const int* __restrict__ dst,
                                               int* __restrict__ off, int E) {
    int e = blockIdx.x * 256 + threadIdx.x;
    if (e < E) atomicAdd(&off[dst[e]], 1);
}

// Block-local exclusive scan of deg (in place) + dis = rsqrt(deg+1) + block sums.
__global__ __launch_bounds__(256) void k_scan_blk(int* __restrict__ off,
                                                  float* __restrict__ dis,
                                                  int* __restrict__ bsum, int N) {
    int t = threadIdx.x;
    int base = blockIdx.x * SCAN_TILE + t * 4;
    int4 d = make_int4(0, 0, 0, 0);
    if (base + 3 < N) d = *(const int4*)(off + base);
    else {
        if (base + 0 < N) d.x = off[base + 0];
        if (base + 1 < N) d.y = off[base + 1];
        if (base + 2 < N) d.z = off[base + 2];
    }
    if (base + 0 < N) dis[base + 0] = rsqrtf((float)(d.x + 1));
    if (base + 1 < N) dis[base + 1] = rsqrtf((float)(d.y + 1));
    if (base + 2 < N) dis[base + 2] = rsqrtf((float)(d.z + 1));
    if (base + 3 < N) dis[base + 3] = rsqrtf((float)(d.w + 1));

    int tsum = d.x + d.y + d.z + d.w;
    int lane = t & 63;
    int incl = tsum;
    #pragma unroll
    for (int ofs = 1; ofs < 64; ofs <<= 1) {
        int u = __shfl_up(incl, ofs);
        if (lane >= ofs) incl += u;
    }
    __shared__ int wsum[4];
    if (lane == 63) wsum[t >> 6] = incl;
    __syncthreads();
    int w = t >> 6;
    int woff = 0;
    for (int i = 0; i < w; ++i) woff += wsum[i];

    int run = woff + incl - tsum;  // exclusive prefix (block-local)
    if (base + 0 < N) off[base + 0] = run; run += d.x;
    if (base + 1 < N) off[base + 1] = run; run += d.y;
    if (base + 2 < N) off[base + 2] = run; run += d.z;
    if (base + 3 < N) off[base + 3] = run;
    if (t == 255) bsum[blockIdx.x] = woff + incl;  // block total
}

__global__ __launch_bounds__(256) void k_scan_add(int* __restrict__ off,
                                                  const int* __restrict__ bsum, int N) {
    int bid = blockIdx.x;
    if (bid == 0) return;
    int p = 0;
    for (int i = 0; i < bid; ++i) p += bsum[i];
    int base = bid * SCAN_TILE + threadIdx.x * 4;
    if (base + 3 < N) {
        int4 v = *(const int4*)(off + base);
        v.x += p; v.y += p; v.z += p; v.w += p;
        *(int4*)(off + base) = v;
    } else {
        if (base + 0 < N) off[base + 0] += p;
        if (base + 1 < N) off[base + 1] += p;
        if (base + 2 < N) off[base + 2] += p;
    }
}

// csr fill: pos = off[dst]++ ; csr[pos] = src. After this, off[v] = excl_prefix[v+1].
__global__ __launch_bounds__(256) void k_fill(const int* __restrict__ src,
                                              const int* __restrict__ dst,
                                              int* __restrict__ off,
                                              int* __restrict__ csr, int E) {
    int e = blockIdx.x * 256 + threadIdx.x;
    if (e >= E) return;
    int pos = atomicAdd(&off[dst[e]], 1);
    csr[pos] = src[e];
}

// Convert all 4 weight matrices (fp32 128x128) into MFMA B-fragment layout,
// bf16 hi/lo planes. Per matrix: [2 planes][4 ksteps][8 ctiles][64 lanes][8] ushort.
__global__ __launch_bounds__(256) void k_wconv(const float* __restrict__ W_in,
                                               const float* __restrict__ Ws,
                                               ushort* __restrict__ Wf) {
    int idx = blockIdx.x * 256 + threadIdx.x;   // 4 * 16384
    int m = idx >> 14;
    int e = idx & 16383;
    int k = e >> 7, col = e & 127;
    const float* srcm = (m == 0) ? W_in : (Ws + (m - 1) * 16384);
    float w = srcm[k * 128 + col];
    ushort hi = f2bf(w);
    ushort lo = f2bf(w - bf2f(hi));
    int ks = k >> 5, lk = (k >> 3) & 3, j = k & 7;
    int ct = col >> 4, lane = lk * 16 + (col & 15);
    int o = m * 32768 + (ks * 8 + ct) * 512 + lane * 8 + j;
    Wf[o] = hi;
    Wf[o + 16384] = lo;
}

// x (fp32) -> hh/hl bf16 split pair.
__global__ __launch_bounds__(256) void k_xconv(const float* __restrict__ x,
                                               ushort* __restrict__ hh,
                                               ushort* __restrict__ hl, int total4) {
    int i = blockIdx.x * 256 + threadIdx.x;
    if (i >= total4) return;
    float4 v = ((const float4*)x)[i];
    ushort a0 = f2bf(v.x), a1 = f2bf(v.y), a2 = f2bf(v.z), a3 = f2bf(v.w);
    uint2 ph, pl;
    ph.x = (uint)a0 | ((uint)a1 << 16);
    ph.y = (uint)a2 | ((uint)a3 << 16);
    pl.x = (uint)f2bf(v.x - bf2f(a0)) | ((uint)f2bf(v.y - bf2f(a1)) << 16);
    pl.y = (uint)f2bf(v.z - bf2f(a2)) | ((uint)f2bf(v.w - bf2f(a3)) << 16);
    ((uint2*)hh)[i] = ph;
    ((uint2*)hl)[i] = pl;
}

// MFMA GEMM: out[M,128] = (Ahi+Alo)[M,128] @ W[128,128], 3-term bf16 split.
// Wave = 16 rows x 64 cols (strip = gw>>1, col-half = gw&1) -> 2500 waves.
// A fully preloaded, then __syncthreads (in-place safety for MODE 1).
// MODE 1: write hi/lo split pair row-major (+bias).
// MODE 0: write bf16 into SLICED xwb [slice=col/64][row][col%64] (x scale).
template<int MODE>
__global__ __launch_bounds__(256) void k_mgemm(const ushort* Ahi, const ushort* Alo,
                                               const ushort* __restrict__ Wf,
                                               const float* __restrict__ bias,
                                               const float* __restrict__ scale,
                                               ushort* xwb, ushort* outhi,
                                               ushort* outlo, int M) {
    int l = threadIdx.x & 63;
    int gw = blockIdx.x * 4 + (threadIdx.x >> 6);
    int strip = gw >> 1, ch = gw & 1;
    int r0 = strip * 16;
    int lr = l & 15, lk = l >> 4;
    int ar = r0 + lr; if (ar >= M) ar = M - 1;

    // preload ALL A fragments for this wave (8 x 16B)
    s8v ah[4], al[4];
    #pragma unroll
    for (int ks = 0; ks < 4; ++ks) {
        ah[ks] = *(const s8v*)(Ahi + (long long)ar * HDIM + lk * 8 + ks * 32);
        al[ks] = *(const s8v*)(Alo + (long long)ar * HDIM + lk * 8 + ks * 32);
    }
    __syncthreads();   // all A reads done before any in-place write below

    f4v acc[4];
    #pragma unroll
    for (int c = 0; c < 4; ++c) acc[c] = (f4v){0.f, 0.f, 0.f, 0.f};

    #pragma unroll
    for (int ks = 0; ks < 4; ++ks) {
        const ushort* wb = Wf + (ks * 8 + ch * 4) * 512 + l * 8;
        #pragma unroll
        for (int c = 0; c < 4; ++c) {
            s8v bh = *(const s8v*)(wb + c * 512);
            s8v bl = *(const s8v*)(wb + 16384 + c * 512);
            acc[c] = __builtin_amdgcn_mfma_f32_16x16x32_bf16(ah[ks], bh, acc[c], 0, 0, 0);
            acc[c] = __builtin_amdgcn_mfma_f32_16x16x32_bf16(ah[ks], bl, acc[c], 0, 0, 0);
            acc[c] = __builtin_amdgcn_mfma_f32_16x16x32_bf16(al[ks], bh, acc[c], 0, 0, 0);
        }
    }

    if (r0 >= M) return;
    float bbv[4], sc[4];
    #pragma unroll
    for (int c = 0; c < 4; ++c) bbv[c] = bias ? bias[(ch * 4 + c) * 16 + lr] : 0.f;
    #pragma unroll
    for (int j = 0; j < 4; ++j) sc[j] = scale ? scale[r0 + lk * 4 + j] : 1.f;

    #pragma unroll
    for (int c = 0; c < 4; ++c) {
        #pragma unroll
        for (int j = 0; j < 4; ++j) {
            int row = r0 + lk * 4 + j;
            if (row >= M) continue;
            float o = (acc[c][j] + bbv[c]) * sc[j];
            if (MODE) {
                int col = (ch * 4 + c) * 16 + lr;
                ushort h = f2bf(o);
                outhi[(long long)row * HDIM + col] = h;
                outlo[(long long)row * HDIM + col] = f2bf(o - bf2f(h));
            } else {
                int cc = c * 16 + lr;   // col within 64-col slice ch
                xwb[((long long)ch * M + row) * 64 + cc] = f2bf(o);
            }
        }
    }
}

// Pull aggregation over SLICED bf16 xwb ([sl][row][64], 2.5MB/slice).
// slice = blockIdx&1 -> each XCD (blockIdx%8 round-robin) touches one slice
// -> gathers XCD-L2-resident. Wave = one node; half-wave = one edge
// (32 lanes x ushort2 = 128B row-slice); 16 edges (8 loads, 2KB) in flight;
// scalar index block of 16; 8/4/2/1 tails; shfl_xor(32) reduce.
// LAST: write fp32 d_out; else bf16 hi/lo split pair (row-major).
template<int LAST>
__global__ __launch_bounds__(256) void k_agg(const int* __restrict__ off,
                                             const int* __restrict__ csr,
                                             const float* __restrict__ dis,
                                             const ushort* __restrict__ xwb,
                                             const float* __restrict__ b,
                                             float* __restrict__ outf,
                                             ushort* __restrict__ outhi,
                                             ushort* __restrict__ outlo, int N) {
    int lane = threadIdx.x & 63;
    int wv = threadIdx.x >> 6;
    int hl = lane & 31, half = lane >> 5;
    int sl = blockIdx.x & 1;
    const ushort* xs = xwb + (long long)sl * N * 64;
    int v0 = (blockIdx.x >> 1) * 4 + wv;
    int vstride = (gridDim.x >> 1) * 4;

    float2 bb = ((const float2*)(b + sl * 64))[hl];

#define GATH(sidx, ax, ay)                                                  \
    {                                                                       \
        uint u = *(const uint*)(xs + (long long)(sidx) * 64 + (hl << 1));   \
        ax += bf2f((ushort)u);                                              \
        ay += bf2f((ushort)(u >> 16));                                      \
    }

    for (int v = v0; v < N; v += vstride) {
        int start = (v > 0) ? off[v - 1] : 0;   // off is post-fill: off[v]=excl[v+1]
        int end = off[v];
        float dv = dis[v];

        float ax = 0.f, ay = 0.f;
        if (half == 0) GATH(v, ax, ay);          // self term

        int i = start;
        for (; i + 16 <= end; i += 16) {
            int ib = __builtin_amdgcn_readfirstlane(i);
            int c[16];
            #pragma unroll
            for (int j = 0; j < 16; ++j) c[j] = csr[ib + j];
            #pragma unroll
            for (int j = 0; j < 8; ++j) {
                int s = half ? c[2 * j + 1] : c[2 * j];
                GATH(s, ax, ay);
            }
        }
        if (i + 8 <= end) {
            int ib = __builtin_amdgcn_readfirstlane(i);
            int c[8];
            #pragma unroll
            for (int j = 0; j < 8; ++j) c[j] = csr[ib + j];
            #pragma unroll
            for (int j = 0; j < 4; ++j) {
                int s = half ? c[2 * j + 1] : c[2 * j];
                GATH(s, ax, ay);
            }
            i += 8;
        }
        if (i + 4 <= end) {
            int ib = __builtin_amdgcn_readfirstlane(i);
            int c0 = csr[ib], c1 = csr[ib + 1], c2 = csr[ib + 2], c3 = csr[ib + 3];
            int sA = half ? c1 : c0;
            int sB = half ? c3 : c2;
            GATH(sA, ax, ay);
            GATH(sB, ax, ay);
            i += 4;
        }
        if (i + 2 <= end) {
            int ib = __builtin_amdgcn_readfirstlane(i);
            int c0 = csr[ib], c1 = csr[ib + 1];
            int s = half ? c1 : c0;
            GATH(s, ax, ay);
            i += 2;
        }
        if (i < end && half == 0) {
            int s = csr[__builtin_amdgcn_readfirstlane(i)];
            GATH(s, ax, ay);
        }

        ax += __shfl_xor(ax, 32);
        ay += __shfl_xor(ay, 32);

        if (half == 0) {
            float ox = fmaxf(fmaf(dv, ax, bb.x), 0.f);
            float oy = fmaxf(fmaf(dv, ay, bb.y), 0.f);
            long long oidx = (long long)v * HDIM + sl * 64 + (hl << 1);
            if (LAST) {
                *(float2*)(outf + oidx) = make_float2(ox, oy);
            } else {
                ushort h0 = f2bf(ox), h1 = f2bf(oy);
                *(uint*)(outhi + oidx) = (uint)h0 | ((uint)h1 << 16);
                uint pl = (uint)f2bf(ox - bf2f(h0)) | ((uint)f2bf(oy - bf2f(h1)) << 16);
                *(uint*)(outlo + oidx) = pl;
            }
        }
    }
#undef GATH
}

extern "C" void kernel_launch(void* const* d_in, const int* in_sizes, int n_in,
                              void* d_out, int out_size, void* d_ws, size_t ws_size,
                              hipStream_t stream) {
    const float* x    = (const float*)d_in[0];
    const int*   ei   = (const int*)d_in[1];   // [2, E]: first E = src, next E = dst
    const float* W_in = (const float*)d_in[2];
    const float* b_in = (const float*)d_in[3];
    const float* Ws   = (const float*)d_in[4]; // [3,128,128]
    const float* bs   = (const float*)d_in[5]; // [3,128]

    const int N = in_sizes[0] / HDIM;
    const int E = in_sizes[1] / 2;
    const int* src = ei;
    const int* dst = ei + E;

    float*  dis = (float*)d_ws;                      // N floats
    int*    off = (int*)(dis + N);                   // N ints
    int*    csr = off + N;                           // E ints (first ~32 = scan bsums, transient)
    ushort* hh  = (ushort*)(csr + E);                // N*128 bf16 (h hi)
    ushort* hl  = hh + (long long)N * HDIM;          // N*128 bf16 (h lo)
    ushort* xwb = hl + (long long)N * HDIM;          // 2 x N x 64 bf16 (sliced, dis-prescaled)
    ushort* Wf  = (ushort*)d_out;                    // 4*64KB scratch, overwritten by last agg

    int nb_N    = (N + 255) / 256;
    int nb_E    = (E + 255) / 256;
    int nb_scan = (N + SCAN_TILE - 1) / SCAN_TILE;
    int nwaves  = ((N + 15) / 16) * 2;
    int nb_mg   = (nwaves + 3) / 4;
    int nb_x4   = (N * (HDIM / 4) + 255) / 256;
    int nb_agg  = 2048;

    // CSR build + dis
    k_zero    <<<nb_N,    256, 0, stream>>>(off, N);
    k_count   <<<nb_E,    256, 0, stream>>>(dst, off, E);
    k_scan_blk<<<nb_scan, 256, 0, stream>>>(off, dis, csr, N);
    k_scan_add<<<nb_scan, 256, 0, stream>>>(off, csr, N);
    k_fill    <<<nb_E,    256, 0, stream>>>(src, dst, off, csr, E);

    // weight fragments (d_out scratch) + x -> bf16 split
    k_wconv<<<256, 256, 0, stream>>>(W_in, Ws, Wf);
    k_xconv<<<nb_x4, 256, 0, stream>>>(x, hh, hl, N * (HDIM / 4));

    // h0 = x @ W_in + b_in   (bf16-split output, in place; synced inside)
    k_mgemm<1><<<nb_mg, 256, 0, stream>>>(hh, hl, Wf, b_in, nullptr,
                                          nullptr, hh, hl, N);

    for (int layer = 0; layer < 3; ++layer) {
        const ushort* Wfm = Wf + (long long)(layer + 1) * 32768;
        const float* b = bs + (long long)layer * HDIM;
        // xwb = bf16( (h @ W) * dis[row] ), sliced layout
        k_mgemm<0><<<nb_mg, 256, 0, stream>>>(hh, hl, Wfm, nullptr, dis,
                                              xwb, nullptr, nullptr, N);
        if (layer == 2)
            k_agg<1><<<nb_agg, 256, 0, stream>>>(off, csr, dis, xwb, b,
                                                 (float*)d_out, nullptr, nullptr, N);
        else
            k_agg<0><<<nb_agg, 256, 0, stream>>>(off, csr, dis, xwb, b,
                                                 nullptr, hh, hl, N);
    }
}

// Round 10
// 196.663 us; speedup vs baseline: 1.6338x; 1.6338x over previous
//
#include <hip/hip_runtime.h>
#include <hip/hip_bf16.h>

// GCN encoder: h = relu(Agg(h @ W)) x3 after input linear.
// N=20000 nodes, E=640000 edges, H=128.
// R1->R2: CSR pull-agg replaced atomics (3330->367us).
// R2->R3: bigger GEMM tiles (367->331us).
// R3->R4: parallel scan; 128-row GEMM blocks (331->274us).
// R4->R5: global-broadcast GEMM -> latency regression (355us).
// R5->R6: LDS-broadcast GEMM (282us).
// R6->R7: GEMMs on matrix pipe via 3-term bf16 split (245us).
// R7->R8: 4-slice fp32 agg -> regression (260us): MLP cut 4x.
// R8->R9: bf16 payload + 2-slice agg: FETCH 107->20.5MB (L2-slicing works!)
//         but int c[16] got PromoteAlloca'd to LDS (LDS_Block_Size=16384,
//         2e7 bank conflicts, WRITE 42MB spill traffic) -> 65us/agg, 321 total.
// R9->R10: same structure, index blocks as named int4/int2 scalars so the
//         array never exists -> no LDS, no conflicts. (guide rule #20)
// ws layout: [dis: N f][off: N i][csr: E i][hh: N*128 bf16][hl: N*128 bf16]
//            [xwb: 2 slices x N x 64 bf16]

#define HDIM 128
#define SCAN_TILE 1024

typedef __attribute__((ext_vector_type(8))) short s8v;
typedef __attribute__((ext_vector_type(4))) float f4v;

__device__ __forceinline__ ushort f2bf(float f) {
    uint u = __float_as_uint(f);
    u += 0x7FFFu + ((u >> 16) & 1u);      // round-to-nearest-even
    return (ushort)(u >> 16);
}
__device__ __forceinline__ float bf2f(ushort h) {
    return __uint_as_float(((uint)h) << 16);
}

__global__ __launch_bounds__(256) void k_zero(int* __restrict__ off, int N) {
    int i = blockIdx.x * 256 + threadIdx.x;
    if (i < N) off[i] = 0;
}

__global__ __launch_bounds__(256) void k_count(const int* __restrict__ dst,
                                               int* __restrict__ off, int E) {
    int e = blockIdx.x * 256 + threadIdx.x;
    if (e < E) atomicAdd(&off[dst[e]], 1);
}

// Block-local exclusive scan of deg (in place) + dis = rsqrt(deg+1) + block sums.
__global__ __launch_bounds__(256) void k_scan_blk(int* __restrict__ off,
                                                  float* __restrict__ dis,
                                                  int* __restrict__ bsum, int N) {
    int t = threadIdx.x;
    int base = blockIdx.x * SCAN_TILE + t * 4;
    int4 d = make_int4(0, 0, 0, 0);
    if (base + 3 < N) d = *(const int4*)(off + base);
    else {
        if (base + 0 < N) d.x = off[base + 0];
        if (base + 1 < N) d.y = off[base + 1];
        if (base + 2 < N) d.z = off[base + 2];
    }
    if (base + 0 < N) dis[base + 0] = rsqrtf((float)(d.x + 1));
    if (base + 1 < N) dis[base + 1] = rsqrtf((float)(d.y + 1));
    if (base + 2 < N) dis[base + 2] = rsqrtf((float)(d.z + 1));
    if (base + 3 < N) dis[base + 3] = rsqrtf((float)(d.w + 1));

    int tsum = d.x + d.y + d.z + d.w;
    int lane = t & 63;
    int incl = tsum;
    #pragma unroll
    for (int ofs = 1; ofs < 64; ofs <<= 1) {
        int u = __shfl_up(incl, ofs);
        if (lane >= ofs) incl += u;
    }
    __shared__ int wsum[4];
    if (lane == 63) wsum[t >> 6] = incl;
    __syncthreads();
    int w = t >> 6;
    int woff = 0;
    for (int i = 0; i < w; ++i) woff += wsum[i];

    int run = woff + incl - tsum;  // exclusive prefix (block-local)
    if (base + 0 < N) off[base + 0] = run; run += d.x;
    if (base + 1 < N) off[base + 1] = run; run += d.y;
    if (base + 2 < N) off[base + 2] = run; run += d.z;
    if (base + 3 < N) off[base + 3] = run;
    if (t == 255) bsum[blockIdx.x] = woff + incl;  // block total
}

__global__ __launch_bounds__(256) void k_scan_add(int* __restrict__ off,
                                                  const int* __restrict__ bsum, int N) {
    int bid = blockIdx.x;
    if (bid == 0) return;
    int p = 0;
    for (int i = 0; i < bid; ++i) p += bsum[i];
    int base = bid * SCAN_TILE + threadIdx.x * 4;
    if (base + 3 < N) {
        int4 v = *(const int4*)(off + base);
        v.x += p; v.y += p; v.z += p; v.w += p;
        *(int4*)(off + base) = v;
    } else {
        if (base + 0 < N) off[base + 0] += p;
        if (base + 1 < N) off[base + 1] += p;
        if (base + 2 < N) off[base + 2] += p;
    }
}

// csr fill: pos = off[dst]++ ; csr[pos] = src. After this, off[v] = excl_prefix[v+1].
__global__ __launch_bounds__(256) void k_fill(const int* __restrict__ src,
                                              const int* __restrict__ dst,
                                              int* __restrict__ off,
                                              int* __restrict__ csr, int E) {
    int e = blockIdx.x * 256 + threadIdx.x;
    if (e >= E) return;
    int pos = atomicAdd(&off[dst[e]], 1);
    csr[pos] = src[e];
}

// Convert all 4 weight matrices (fp32 128x128) into MFMA B-fragment layout,
// bf16 hi/lo planes. Per matrix: [2 planes][4 ksteps][8 ctiles][64 lanes][8] ushort.
__global__ __launch_bounds__(256) void k_wconv(const float* __restrict__ W_in,
                                               const float* __restrict__ Ws,
                                               ushort* __restrict__ Wf) {
    int idx = blockIdx.x * 256 + threadIdx.x;   // 4 * 16384
    int m = idx >> 14;
    int e = idx & 16383;
    int k = e >> 7, col = e & 127;
    const float* srcm = (m == 0) ? W_in : (Ws + (m - 1) * 16384);
    float w = srcm[k * 128 + col];
    ushort hi = f2bf(w);
    ushort lo = f2bf(w - bf2f(hi));
    int ks = k >> 5, lk = (k >> 3) & 3, j = k & 7;
    int ct = col >> 4, lane = lk * 16 + (col & 15);
    int o = m * 32768 + (ks * 8 + ct) * 512 + lane * 8 + j;
    Wf[o] = hi;
    Wf[o + 16384] = lo;
}

// x (fp32) -> hh/hl bf16 split pair.
__global__ __launch_bounds__(256) void k_xconv(const float* __restrict__ x,
                                               ushort* __restrict__ hh,
                                               ushort* __restrict__ hl, int total4) {
    int i = blockIdx.x * 256 + threadIdx.x;
    if (i >= total4) return;
    float4 v = ((const float4*)x)[i];
    ushort a0 = f2bf(v.x), a1 = f2bf(v.y), a2 = f2bf(v.z), a3 = f2bf(v.w);
    uint2 ph, pl;
    ph.x = (uint)a0 | ((uint)a1 << 16);
    ph.y = (uint)a2 | ((uint)a3 << 16);
    pl.x = (uint)f2bf(v.x - bf2f(a0)) | ((uint)f2bf(v.y - bf2f(a1)) << 16);
    pl.y = (uint)f2bf(v.z - bf2f(a2)) | ((uint)f2bf(v.w - bf2f(a3)) << 16);
    ((uint2*)hh)[i] = ph;
    ((uint2*)hl)[i] = pl;
}

// MFMA GEMM: out[M,128] = (Ahi+Alo)[M,128] @ W[128,128], 3-term bf16 split.
// Wave = 16 rows x 64 cols (strip = gw>>1, col-half = gw&1) -> 2500 waves.
// MODE 1: write hi/lo split pair row-major (+bias).
// MODE 0: write bf16 into SLICED xwb [slice=col/64][row][col%64] (x scale).
template<int MODE>
__global__ __launch_bounds__(256) void k_mgemm(const ushort* Ahi, const ushort* Alo,
                                               const ushort* __restrict__ Wf,
                                               const float* __restrict__ bias,
                                               const float* __restrict__ scale,
                                               ushort* xwb, ushort* outhi,
                                               ushort* outlo, int M) {
    int l = threadIdx.x & 63;
    int gw = blockIdx.x * 4 + (threadIdx.x >> 6);
    int strip = gw >> 1, ch = gw & 1;
    int r0 = strip * 16;
    int lr = l & 15, lk = l >> 4;
    int ar = r0 + lr; if (ar >= M) ar = M - 1;

    // preload ALL A fragments for this wave (8 x 16B)
    s8v ah0 = *(const s8v*)(Ahi + (long long)ar * HDIM + lk * 8);
    s8v ah1 = *(const s8v*)(Ahi + (long long)ar * HDIM + lk * 8 + 32);
    s8v ah2 = *(const s8v*)(Ahi + (long long)ar * HDIM + lk * 8 + 64);
    s8v ah3 = *(const s8v*)(Ahi + (long long)ar * HDIM + lk * 8 + 96);
    s8v al0 = *(const s8v*)(Alo + (long long)ar * HDIM + lk * 8);
    s8v al1 = *(const s8v*)(Alo + (long long)ar * HDIM + lk * 8 + 32);
    s8v al2 = *(const s8v*)(Alo + (long long)ar * HDIM + lk * 8 + 64);
    s8v al3 = *(const s8v*)(Alo + (long long)ar * HDIM + lk * 8 + 96);
    __syncthreads();   // all A reads done before any in-place write below

    f4v acc[4];
    #pragma unroll
    for (int c = 0; c < 4; ++c) acc[c] = (f4v){0.f, 0.f, 0.f, 0.f};

#define KSTEP(AH, AL, ksi)                                                          \
    {                                                                               \
        const ushort* wb = Wf + ((ksi) * 8 + ch * 4) * 512 + l * 8;                 \
        _Pragma("unroll")                                                           \
        for (int c = 0; c < 4; ++c) {                                               \
            s8v bh = *(const s8v*)(wb + c * 512);                                   \
            s8v bl = *(const s8v*)(wb + 16384 + c * 512);                           \
            acc[c] = __builtin_amdgcn_mfma_f32_16x16x32_bf16(AH, bh, acc[c], 0,0,0);\
            acc[c] = __builtin_amdgcn_mfma_f32_16x16x32_bf16(AH, bl, acc[c], 0,0,0);\
            acc[c] = __builtin_amdgcn_mfma_f32_16x16x32_bf16(AL, bh, acc[c], 0,0,0);\
        }                                                                           \
    }
    KSTEP(ah0, al0, 0)
    KSTEP(ah1, al1, 1)
    KSTEP(ah2, al2, 2)
    KSTEP(ah3, al3, 3)
#undef KSTEP

    if (r0 >= M) return;
    float bbv[4], sc[4];
    #pragma unroll
    for (int c = 0; c < 4; ++c) bbv[c] = bias ? bias[(ch * 4 + c) * 16 + lr] : 0.f;
    #pragma unroll
    for (int j = 0; j < 4; ++j) sc[j] = scale ? scale[r0 + lk * 4 + j] : 1.f;

    #pragma unroll
    for (int c = 0; c < 4; ++c) {
        #pragma unroll
        for (int j = 0; j < 4; ++j) {
            int row = r0 + lk * 4 + j;
            if (row >= M) continue;
            float o = (acc[c][j] + bbv[c]) * sc[j];
            if (MODE) {
                int col = (ch * 4 + c) * 16 + lr;
                ushort h = f2bf(o);
                outhi[(long long)row * HDIM + col] = h;
                outlo[(long long)row * HDIM + col] = f2bf(o - bf2f(h));
            } else {
                int cc = c * 16 + lr;   // col within 64-col slice ch
                xwb[((long long)ch * M + row) * 64 + cc] = f2bf(o);
            }
        }
    }
}

// Pull aggregation over SLICED bf16 xwb ([sl][row][64], 2.5MB/slice).
// slice = blockIdx&1 -> each XCD (blockIdx%8 round-robin) touches one slice
// -> gathers XCD-L2-resident (R9: FETCH 107->20.5MB). Wave = one node;
// half-wave = one edge (32 lanes x uint = 128B row-slice); 16 edges
// (8 loads) in flight. Index blocks as NAMED int4/int2 scalars -- R9's
// int c[16] was PromoteAlloca'd to LDS (16KB, 2e7 bank conflicts).
// LAST: write fp32 d_out; else bf16 hi/lo split pair (row-major).
template<int LAST>
__global__ __launch_bounds__(256) void k_agg(const int* __restrict__ off,
                                             const int* __restrict__ csr,
                                             const float* __restrict__ dis,
                                             const ushort* __restrict__ xwb,
                                             const float* __restrict__ b,
                                             float* __restrict__ outf,
                                             ushort* __restrict__ outhi,
                                             ushort* __restrict__ outlo, int N) {
    int lane = threadIdx.x & 63;
    int wv = threadIdx.x >> 6;
    int hl = lane & 31, half = lane >> 5;
    int sl = blockIdx.x & 1;
    const ushort* xs = xwb + (long long)sl * N * 64;
    int v0 = (blockIdx.x >> 1) * 4 + wv;
    int vstride = (gridDim.x >> 1) * 4;

    float2 bb = ((const float2*)(b + sl * 64))[hl];

#define GATH(sidx, ax, ay)                                                  \
    {                                                                       \
        uint u = *(const uint*)(xs + (long long)(sidx) * 64 + (hl << 1));   \
        ax += bf2f((ushort)u);                                              \
        ay += bf2f((ushort)(u >> 16));                                      \
    }

    for (int v = v0; v < N; v += vstride) {
        int start = (v > 0) ? off[v - 1] : 0;   // off is post-fill: off[v]=excl[v+1]
        int end = off[v];
        float dv = dis[v];

        float ax = 0.f, ay = 0.f;
        if (half == 0) GATH(v, ax, ay);          // self term

        int i = start;
        for (; i + 16 <= end; i += 16) {
            int ib = __builtin_amdgcn_readfirstlane(i);
            int4 ca = *(const int4*)(csr + ib);
            int4 cb = *(const int4*)(csr + ib + 4);
            int4 cc = *(const int4*)(csr + ib + 8);
            int4 cd = *(const int4*)(csr + ib + 12);
            int sA = half ? ca.y : ca.x;
            int sB = half ? ca.w : ca.z;
            int sC = half ? cb.y : cb.x;
            int sD = half ? cb.w : cb.z;
            int sE = half ? cc.y : cc.x;
            int sF = half ? cc.w : cc.z;
            int sG = half ? cd.y : cd.x;
            int sH = half ? cd.w : cd.z;
            GATH(sA, ax, ay); GATH(sB, ax, ay);
            GATH(sC, ax, ay); GATH(sD, ax, ay);
            GATH(sE, ax, ay); GATH(sF, ax, ay);
            GATH(sG, ax, ay); GATH(sH, ax, ay);
        }
        if (i + 8 <= end) {
            int ib = __builtin_amdgcn_readfirstlane(i);
            int4 ca = *(const int4*)(csr + ib);
            int4 cb = *(const int4*)(csr + ib + 4);
            int sA = half ? ca.y : ca.x;
            int sB = half ? ca.w : ca.z;
            int sC = half ? cb.y : cb.x;
            int sD = half ? cb.w : cb.z;
            GATH(sA, ax, ay); GATH(sB, ax, ay);
            GATH(sC, ax, ay); GATH(sD, ax, ay);
            i += 8;
        }
        if (i + 4 <= end) {
            int ib = __builtin_amdgcn_readfirstlane(i);
            int4 ca = *(const int4*)(csr + ib);
            int sA = half ? ca.y : ca.x;
            int sB = half ? ca.w : ca.z;
            GATH(sA, ax, ay); GATH(sB, ax, ay);
            i += 4;
        }
        if (i + 2 <= end) {
            int ib = __builtin_amdgcn_readfirstlane(i);
            int2 ca = *(const int2*)(csr + ib);
            int s = half ? ca.y : ca.x;
            GATH(s, ax, ay);
            i += 2;
        }
        if (i < end && half == 0) {
            int s = csr[__builtin_amdgcn_readfirstlane(i)];
            GATH(s, ax, ay);
        }

        ax += __shfl_xor(ax, 32);
        ay += __shfl_xor(ay, 32);

        if (half == 0) {
            float ox = fmaxf(fmaf(dv, ax, bb.x), 0.f);
            float oy = fmaxf(fmaf(dv, ay, bb.y), 0.f);
            long long oidx = (long long)v * HDIM + sl * 64 + (hl << 1);
            if (LAST) {
                *(float2*)(outf + oidx) = make_float2(ox, oy);
            } else {
                ushort h0 = f2bf(ox), h1 = f2bf(oy);
                *(uint*)(outhi + oidx) = (uint)h0 | ((uint)h1 << 16);
                uint pl = (uint)f2bf(ox - bf2f(h0)) | ((uint)f2bf(oy - bf2f(h1)) << 16);
                *(uint*)(outlo + oidx) = pl;
            }
        }
    }
#undef GATH
}

extern "C" void kernel_launch(void* const* d_in, const int* in_sizes, int n_in,
                              void* d_out, int out_size, void* d_ws, size_t ws_size,
                              hipStream_t stream) {
    const float* x    = (const float*)d_in[0];
    const int*   ei   = (const int*)d_in[1];   // [2, E]: first E = src, next E = dst
    const float* W_in = (const float*)d_in[2];
    const float* b_in = (const float*)d_in[3];
    const float* Ws   = (const float*)d_in[4]; // [3,128,128]
    const float* bs   = (const float*)d_in[5]; // [3,128]

    const int N = in_sizes[0] / HDIM;
    const int E = in_sizes[1] / 2;
    const int* src = ei;
    const int* dst = ei + E;

    float*  dis = (float*)d_ws;                      // N floats
    int*    off = (int*)(dis + N);                   // N ints
    int*    csr = off + N;                           // E ints (first ~32 = scan bsums, transient)
    ushort* hh  = (ushort*)(csr + E);                // N*128 bf16 (h hi)
    ushort* hl  = hh + (long long)N * HDIM;          // N*128 bf16 (h lo)
    ushort* xwb = hl + (long long)N * HDIM;          // 2 x N x 64 bf16 (sliced, dis-prescaled)
    ushort* Wf  = (ushort*)d_out;                    // 4*64KB scratch, overwritten by last agg

    int nb_N    = (N + 255) / 256;
    int nb_E    = (E + 255) / 256;
    int nb_scan = (N + SCAN_TILE - 1) / SCAN_TILE;
    int nwaves  = ((N + 15) / 16) * 2;
    int nb_mg   = (nwaves + 3) / 4;
    int nb_x4   = (N * (HDIM / 4) + 255) / 256;
    int nb_agg  = 2048;

    // CSR build + dis
    k_zero    <<<nb_N,    256, 0, stream>>>(off, N);
    k_count   <<<nb_E,    256, 0, stream>>>(dst, off, E);
    k_scan_blk<<<nb_scan, 256, 0, stream>>>(off, dis, csr, N);
    k_scan_add<<<nb_scan, 256, 0, stream>>>(off, csr, N);
    k_fill    <<<nb_E,    256, 0, stream>>>(src, dst, off, csr, E);

    // weight fragments (d_out scratch) + x -> bf16 split
    k_wconv<<<256, 256, 0, stream>>>(W_in, Ws, Wf);
    k_xconv<<<nb_x4, 256, 0, stream>>>(x, hh, hl, N * (HDIM / 4));

    // h0 = x @ W_in + b_in   (bf16-split output, in place; synced inside)
    k_mgemm<1><<<nb_mg, 256, 0, stream>>>(hh, hl, Wf, b_in, nullptr,
                                          nullptr, hh, hl, N);

    for (int layer = 0; layer < 3; ++layer) {
        const ushort* Wfm = Wf + (long long)(layer + 1) * 32768;
        const float* b = bs + (long long)layer * HDIM;
        // xwb = bf16( (h @ W) * dis[row] ), sliced layout
        k_mgemm<0><<<nb_mg, 256, 0, stream>>>(hh, hl, Wfm, nullptr, dis,
                                              xwb, nullptr, nullptr, N);
        if (layer == 2)
            k_agg<1><<<nb_agg, 256, 0, stream>>>(off, csr, dis, xwb, b,
                                                 (float*)d_out, nullptr, nullptr, N);
        else
            k_agg<0><<<nb_agg, 256, 0, stream>>>(off, csr, dis, xwb, b,
                                                 nullptr, hh, hl, N);
    }
}

// Round 11
// 193.174 us; speedup vs baseline: 1.6633x; 1.0181x over previous
//
#include <hip/hip_runtime.h>
#include <hip/hip_bf16.h>

// GCN encoder: h = relu(Agg(h @ W)) x3 after input linear.
// N=20000 nodes, E=640000 edges, H=128.
// R1->R2: CSR pull-agg replaced atomics (3330->367us).
// R2->R3: bigger GEMM tiles (367->331us).  R3->R4: parallel scan (331->274).
// R4->R5: global-broadcast GEMM regression (355). R5->R6: LDS-broadcast (282).
// R6->R7: GEMMs on matrix pipe via 3-term bf16 split (245us).
// R7->R8: 4-slice fp32 agg regression (260): MLP cut 4x.
// R8->R9: bf16 payload + 2-slice agg: FETCH 107->20.5MB but int c[16]
//         PromoteAlloca'd to LDS -> 2e7 bank conflicts (321us).
// R9->R10: named int4 scalars, no LDS (197us).
// R10->R11: agg quarter-wave edges: lane=(q=edge-slot, t=col-group), uint2
//         (8B) payload loads -> half the load instrs, 4 edges/round, 32-edge
//         unroll (8 loads/lane in flight), shfl_xor(16/32) reduce, float4/
//         uint2 coalesced epilogue, int2 off load, 1-round predicated tail;
//         zero+wconv+xconv merged into k_pre (-2 dispatches).
// ws layout: [dis: N f][off: N i][csr: E i][hh: N*128 bf16][hl: N*128 bf16]
//            [xwb: 2 slices x N x 64 bf16]

#define HDIM 128
#define SCAN_TILE 1024

typedef __attribute__((ext_vector_type(8))) short s8v;
typedef __attribute__((ext_vector_type(4))) float f4v;

__device__ __forceinline__ ushort f2bf(float f) {
    uint u = __float_as_uint(f);
    u += 0x7FFFu + ((u >> 16) & 1u);      // round-to-nearest-even
    return (ushort)(u >> 16);
}
__device__ __forceinline__ float bf2f(ushort h) {
    return __uint_as_float(((uint)h) << 16);
}

__global__ __launch_bounds__(256) void k_count(const int* __restrict__ dst,
                                               int* __restrict__ off, int E) {
    int e = blockIdx.x * 256 + threadIdx.x;
    if (e < E) atomicAdd(&off[dst[e]], 1);
}

// Block-local exclusive scan of deg (in place) + dis = rsqrt(deg+1) + block sums.
__global__ __launch_bounds__(256) void k_scan_blk(int* __restrict__ off,
                                                  float* __restrict__ dis,
                                                  int* __restrict__ bsum, int N) {
    int t = threadIdx.x;
    int base = blockIdx.x * SCAN_TILE + t * 4;
    int4 d = make_int4(0, 0, 0, 0);
    if (base + 3 < N) d = *(const int4*)(off + base);
    else {
        if (base + 0 < N) d.x = off[base + 0];
        if (base + 1 < N) d.y = off[base + 1];
        if (base + 2 < N) d.z = off[base + 2];
    }
    if (base + 0 < N) dis[base + 0] = rsqrtf((float)(d.x + 1));
    if (base + 1 < N) dis[base + 1] = rsqrtf((float)(d.y + 1));
    if (base + 2 < N) dis[base + 2] = rsqrtf((float)(d.z + 1));
    if (base + 3 < N) dis[base + 3] = rsqrtf((float)(d.w + 1));

    int tsum = d.x + d.y + d.z + d.w;
    int lane = t & 63;
    int incl = tsum;
    #pragma unroll
    for (int ofs = 1; ofs < 64; ofs <<= 1) {
        int u = __shfl_up(incl, ofs);
        if (lane >= ofs) incl += u;
    }
    __shared__ int wsum[4];
    if (lane == 63) wsum[t >> 6] = incl;
    __syncthreads();
    int w = t >> 6;
    int woff = 0;
    for (int i = 0; i < w; ++i) woff += wsum[i];

    int run = woff + incl - tsum;  // exclusive prefix (block-local)
    if (base + 0 < N) off[base + 0] = run; run += d.x;
    if (base + 1 < N) off[base + 1] = run; run += d.y;
    if (base + 2 < N) off[base + 2] = run; run += d.z;
    if (base + 3 < N) off[base + 3] = run;
    if (t == 255) bsum[blockIdx.x] = woff + incl;  // block total
}

__global__ __launch_bounds__(256) void k_scan_add(int* __restrict__ off,
                                                  const int* __restrict__ bsum, int N) {
    int bid = blockIdx.x;
    if (bid == 0) return;
    int p = 0;
    for (int i = 0; i < bid; ++i) p += bsum[i];
    int base = bid * SCAN_TILE + threadIdx.x * 4;
    if (base + 3 < N) {
        int4 v = *(const int4*)(off + base);
        v.x += p; v.y += p; v.z += p; v.w += p;
        *(int4*)(off + base) = v;
    } else {
        if (base + 0 < N) off[base + 0] += p;
        if (base + 1 < N) off[base + 1] += p;
        if (base + 2 < N) off[base + 2] += p;
    }
}

// csr fill: pos = off[dst]++ ; csr[pos] = src. After this, off[v] = excl_prefix[v+1].
__global__ __launch_bounds__(256) void k_fill(const int* __restrict__ src,
                                              const int* __restrict__ dst,
                                              int* __restrict__ off,
                                              int* __restrict__ csr, int E) {
    int e = blockIdx.x * 256 + threadIdx.x;
    if (e >= E) return;
    int pos = atomicAdd(&off[dst[e]], 1);
    csr[pos] = src[e];
}

// Merged preprocessing: [0,nbN) zero off; [nbN,nbN+256) wconv; rest xconv.
// wconv: fp32 128x128 -> MFMA B-fragment bf16 hi/lo planes,
//        [2 planes][4 ksteps][8 ctiles][64 lanes][8] ushort per matrix.
// xconv: x fp32 -> hh/hl bf16 split pair.
__global__ __launch_bounds__(256) void k_pre(const float* __restrict__ W_in,
                                             const float* __restrict__ Ws,
                                             ushort* __restrict__ Wf,
                                             const float* __restrict__ x,
                                             ushort* __restrict__ hh,
                                             ushort* __restrict__ hl,
                                             int* __restrict__ off,
                                             int N, int nbN, int total4) {
    int bid = blockIdx.x;
    if (bid < nbN) {
        int i = bid * 256 + threadIdx.x;
        if (i < N) off[i] = 0;
    } else if (bid < nbN + 256) {
        int idx = (bid - nbN) * 256 + threadIdx.x;   // 4 * 16384
        int m = idx >> 14;
        int e = idx & 16383;
        int k = e >> 7, col = e & 127;
        const float* srcm = (m == 0) ? W_in : (Ws + (m - 1) * 16384);
        float w = srcm[k * 128 + col];
        ushort hi = f2bf(w);
        ushort lo = f2bf(w - bf2f(hi));
        int ks = k >> 5, lk = (k >> 3) & 3, j = k & 7;
        int ct = col >> 4, lane = lk * 16 + (col & 15);
        int o = m * 32768 + (ks * 8 + ct) * 512 + lane * 8 + j;
        Wf[o] = hi;
        Wf[o + 16384] = lo;
    } else {
        int i = (bid - nbN - 256) * 256 + threadIdx.x;
        if (i >= total4) return;
        float4 v = ((const float4*)x)[i];
        ushort a0 = f2bf(v.x), a1 = f2bf(v.y), a2 = f2bf(v.z), a3 = f2bf(v.w);
        uint2 ph, pl;
        ph.x = (uint)a0 | ((uint)a1 << 16);
        ph.y = (uint)a2 | ((uint)a3 << 16);
        pl.x = (uint)f2bf(v.x - bf2f(a0)) | ((uint)f2bf(v.y - bf2f(a1)) << 16);
        pl.y = (uint)f2bf(v.z - bf2f(a2)) | ((uint)f2bf(v.w - bf2f(a3)) << 16);
        ((uint2*)hh)[i] = ph;
        ((uint2*)hl)[i] = pl;
    }
}

// MFMA GEMM: out[M,128] = (Ahi+Alo)[M,128] @ W[128,128], 3-term bf16 split.
// Wave = 16 rows x 64 cols (strip = gw>>1, col-half = gw&1) -> 2500 waves.
// MODE 1: write hi/lo split pair row-major (+bias).
// MODE 0: write bf16 into SLICED xwb [slice=col/64][row][col%64] (x scale).
template<int MODE>
__global__ __launch_bounds__(256) void k_mgemm(const ushort* Ahi, const ushort* Alo,
                                               const ushort* __restrict__ Wf,
                                               const float* __restrict__ bias,
                                               const float* __restrict__ scale,
                                               ushort* xwb, ushort* outhi,
                                               ushort* outlo, int M) {
    int l = threadIdx.x & 63;
    int gw = blockIdx.x * 4 + (threadIdx.x >> 6);
    int strip = gw >> 1, ch = gw & 1;
    int r0 = strip * 16;
    int lr = l & 15, lk = l >> 4;
    int ar = r0 + lr; if (ar >= M) ar = M - 1;

    // preload ALL A fragments for this wave (8 x 16B)
    s8v ah0 = *(const s8v*)(Ahi + (long long)ar * HDIM + lk * 8);
    s8v ah1 = *(const s8v*)(Ahi + (long long)ar * HDIM + lk * 8 + 32);
    s8v ah2 = *(const s8v*)(Ahi + (long long)ar * HDIM + lk * 8 + 64);
    s8v ah3 = *(const s8v*)(Ahi + (long long)ar * HDIM + lk * 8 + 96);
    s8v al0 = *(const s8v*)(Alo + (long long)ar * HDIM + lk * 8);
    s8v al1 = *(const s8v*)(Alo + (long long)ar * HDIM + lk * 8 + 32);
    s8v al2 = *(const s8v*)(Alo + (long long)ar * HDIM + lk * 8 + 64);
    s8v al3 = *(const s8v*)(Alo + (long long)ar * HDIM + lk * 8 + 96);
    __syncthreads();   // all A reads done before any in-place write below

    f4v acc[4];
    #pragma unroll
    for (int c = 0; c < 4; ++c) acc[c] = (f4v){0.f, 0.f, 0.f, 0.f};

#define KSTEP(AH, AL, ksi)                                                          \
    {                                                                               \
        const ushort* wb = Wf + ((ksi) * 8 + ch * 4) * 512 + l * 8;                 \
        _Pragma("unroll")                                                           \
        for (int c = 0; c < 4; ++c) {                                               \
            s8v bh = *(const s8v*)(wb + c * 512);                                   \
            s8v bl = *(const s8v*)(wb + 16384 + c * 512);                           \
            acc[c] = __builtin_amdgcn_mfma_f32_16x16x32_bf16(AH, bh, acc[c], 0,0,0);\
            acc[c] = __builtin_amdgcn_mfma_f32_16x16x32_bf16(AH, bl, acc[c], 0,0,0);\
            acc[c] = __builtin_amdgcn_mfma_f32_16x16x32_bf16(AL, bh, acc[c], 0,0,0);\
        }                                                                           \
    }
    KSTEP(ah0, al0, 0)
    KSTEP(ah1, al1, 1)
    KSTEP(ah2, al2, 2)
    KSTEP(ah3, al3, 3)
#undef KSTEP

    if (r0 >= M) return;
    float bbv[4], sc[4];
    #pragma unroll
    for (int c = 0; c < 4; ++c) bbv[c] = bias ? bias[(ch * 4 + c) * 16 + lr] : 0.f;
    #pragma unroll
    for (int j = 0; j < 4; ++j) sc[j] = scale ? scale[r0 + lk * 4 + j] : 1.f;

    #pragma unroll
    for (int c = 0; c < 4; ++c) {
        #pragma unroll
        for (int j = 0; j < 4; ++j) {
            int row = r0 + lk * 4 + j;
            if (row >= M) continue;
            float o = (acc[c][j] + bbv[c]) * sc[j];
            if (MODE) {
                int col = (ch * 4 + c) * 16 + lr;
                ushort h = f2bf(o);
                outhi[(long long)row * HDIM + col] = h;
                outlo[(long long)row * HDIM + col] = f2bf(o - bf2f(h));
            } else {
                int cc = c * 16 + lr;   // col within 64-col slice ch
                xwb[((long long)ch * M + row) * 64 + cc] = f2bf(o);
            }
        }
    }
}

// Pull aggregation over SLICED bf16 xwb ([sl][row][64], 2.5MB/slice).
// slice = blockIdx&1 -> XCD-L2-resident gathers (R9: FETCH 107->20.5MB).
// Quarter-wave edges: lane = (q = lane>>4 edge slot, t = lane&15 col group);
// each lane loads uint2 = 4 cols (8B); one round = 4 edges x 128B;
// 32-edge unroll = 8 independent loads/lane in flight. Indices via scalar
// int4 loads + q-select (named scalars only -- rule #20). shfl_xor(16,32)
// reduce; q==0 lanes write float4 / uint2 pair (256B / 128B coalesced).
// LAST: write fp32 d_out; else bf16 hi/lo split pair (row-major).
template<int LAST>
__global__ __launch_bounds__(256) void k_agg(const int* __restrict__ off,
                                             const int* __restrict__ csr,
                                             const float* __restrict__ dis,
                                             const ushort* __restrict__ xwb,
                                             const float* __restrict__ b,
                                             float* __restrict__ outf,
                                             ushort* __restrict__ outhi,
                                             ushort* __restrict__ outlo, int N) {
    int lane = threadIdx.x & 63;
    int wv = threadIdx.x >> 6;
    int t = lane & 15, q = lane >> 4;
    int sl = blockIdx.x & 1;
    const ushort* xs = xwb + (long long)sl * N * 64;
    int v0 = (blockIdx.x >> 1) * 4 + wv;
    int vstride = (gridDim.x >> 1) * 4;

    float4 bb = ((const float4*)(b + sl * 64))[t];   // cols 4t..4t+3

#define GATH(sidx)                                                          \
    {                                                                       \
        uint2 u = *(const uint2*)(xs + (long long)(sidx) * 64 + (t << 2));  \
        ax += bf2f((ushort)u.x); ay += bf2f((ushort)(u.x >> 16));           \
        az += bf2f((ushort)u.y); aw += bf2f((ushort)(u.y >> 16));           \
    }
#define SEL(c) (q == 0 ? (c).x : q == 1 ? (c).y : q == 2 ? (c).z : (c).w)

    for (int v = v0; v < N; v += vstride) {
        int start, end;
        if (v > 0) { int2 se = *(const int2*)(off + v - 1); start = se.x; end = se.y; }
        else { start = 0; end = off[0]; }
        float dv = dis[v];

        float ax = 0.f, ay = 0.f, az = 0.f, aw = 0.f;
        if (q == 0) GATH(v);                         // self term

        int i = start;
        for (; i + 32 <= end; i += 32) {
            int ib = __builtin_amdgcn_readfirstlane(i);
            int4 c0 = *(const int4*)(csr + ib);
            int4 c1 = *(const int4*)(csr + ib + 4);
            int4 c2 = *(const int4*)(csr + ib + 8);
            int4 c3 = *(const int4*)(csr + ib + 12);
            int4 c4 = *(const int4*)(csr + ib + 16);
            int4 c5 = *(const int4*)(csr + ib + 20);
            int4 c6 = *(const int4*)(csr + ib + 24);
            int4 c7 = *(const int4*)(csr + ib + 28);
            int s0 = SEL(c0), s1 = SEL(c1), s2 = SEL(c2), s3 = SEL(c3);
            int s4 = SEL(c4), s5 = SEL(c5), s6 = SEL(c6), s7 = SEL(c7);
            GATH(s0); GATH(s1); GATH(s2); GATH(s3);
            GATH(s4); GATH(s5); GATH(s6); GATH(s7);
        }
        if (i + 16 <= end) {
            int ib = __builtin_amdgcn_readfirstlane(i);
            int4 c0 = *(const int4*)(csr + ib);
            int4 c1 = *(const int4*)(csr + ib + 4);
            int4 c2 = *(const int4*)(csr + ib + 8);
            int4 c3 = *(const int4*)(csr + ib + 12);
            int s0 = SEL(c0), s1 = SEL(c1), s2 = SEL(c2), s3 = SEL(c3);
            GATH(s0); GATH(s1); GATH(s2); GATH(s3);
            i += 16;
        }
        if (i + 8 <= end) {
            int ib = __builtin_amdgcn_readfirstlane(i);
            int4 c0 = *(const int4*)(csr + ib);
            int4 c1 = *(const int4*)(csr + ib + 4);
            int s0 = SEL(c0), s1 = SEL(c1);
            GATH(s0); GATH(s1);
            i += 8;
        }
        if (i + 4 <= end) {
            int ib = __builtin_amdgcn_readfirstlane(i);
            int4 c0 = *(const int4*)(csr + ib);
            int s0 = SEL(c0);
            GATH(s0);
            i += 4;
        }
        {   // remainder 0..3 edges: one predicated round
            int r = end - i;
            if (q < r) {
                int s = csr[__builtin_amdgcn_readfirstlane(i) + q];
                GATH(s);
            }
        }

        ax += __shfl_xor(ax, 16); ax += __shfl_xor(ax, 32);
        ay += __shfl_xor(ay, 16); ay += __shfl_xor(ay, 32);
        az += __shfl_xor(az, 16); az += __shfl_xor(az, 32);
        aw += __shfl_xor(aw, 16); aw += __shfl_xor(aw, 32);

        if (q == 0) {
            float ox = fmaxf(fmaf(dv, ax, bb.x), 0.f);
            float oy = fmaxf(fmaf(dv, ay, bb.y), 0.f);
            float oz = fmaxf(fmaf(dv, az, bb.z), 0.f);
            float ow = fmaxf(fmaf(dv, aw, bb.w), 0.f);
            long long oidx = (long long)v * HDIM + sl * 64 + (t << 2);
            if (LAST) {
                *(float4*)(outf + oidx) = make_float4(ox, oy, oz, ow);
            } else {
                ushort h0 = f2bf(ox), h1 = f2bf(oy), h2 = f2bf(oz), h3 = f2bf(ow);
                uint2 ph, pl;
                ph.x = (uint)h0 | ((uint)h1 << 16);
                ph.y = (uint)h2 | ((uint)h3 << 16);
                pl.x = (uint)f2bf(ox - bf2f(h0)) | ((uint)f2bf(oy - bf2f(h1)) << 16);
                pl.y = (uint)f2bf(oz - bf2f(h2)) | ((uint)f2bf(ow - bf2f(h3)) << 16);
                *(uint2*)(outhi + oidx) = ph;
                *(uint2*)(outlo + oidx) = pl;
            }
        }
    }
#undef GATH
#undef SEL
}

extern "C" void kernel_launch(void* const* d_in, const int* in_sizes, int n_in,
                              void* d_out, int out_size, void* d_ws, size_t ws_size,
                              hipStream_t stream) {
    const float* x    = (const float*)d_in[0];
    const int*   ei   = (const int*)d_in[1];   // [2, E]: first E = src, next E = dst
    const float* W_in = (const float*)d_in[2];
    const float* b_in = (const float*)d_in[3];
    const float* Ws   = (const float*)d_in[4]; // [3,128,128]
    const float* bs   = (const float*)d_in[5]; // [3,128]

    const int N = in_sizes[0] / HDIM;
    const int E = in_sizes[1] / 2;
    const int* src = ei;
    const int* dst = ei + E;

    float*  dis = (float*)d_ws;                      // N floats
    int*    off = (int*)(dis + N);                   // N ints
    int*    csr = off + N;                           // E ints (first ~32 = scan bsums, transient)
    ushort* hh  = (ushort*)(csr + E);                // N*128 bf16 (h hi)
    ushort* hl  = hh + (long long)N * HDIM;          // N*128 bf16 (h lo)
    ushort* xwb = hl + (long long)N * HDIM;          // 2 x N x 64 bf16 (sliced, dis-prescaled)
    ushort* Wf  = (ushort*)d_out;                    // 4*64KB scratch, overwritten by last agg

    int nb_N    = (N + 255) / 256;
    int nb_E    = (E + 255) / 256;
    int nb_scan = (N + SCAN_TILE - 1) / SCAN_TILE;
    int nwaves  = ((N + 15) / 16) * 2;
    int nb_mg   = (nwaves + 3) / 4;
    int total4  = N * (HDIM / 4);
    int nb_x4   = (total4 + 255) / 256;
    int nb_pre  = nb_N + 256 + nb_x4;
    int nb_agg  = 2048;

    // preprocessing (zero off + weight fragments + x split) in one dispatch
    k_pre<<<nb_pre, 256, 0, stream>>>(W_in, Ws, Wf, x, hh, hl, off, N, nb_N, total4);

    // CSR build + dis
    k_count   <<<nb_E,    256, 0, stream>>>(dst, off, E);
    k_scan_blk<<<nb_scan, 256, 0, stream>>>(off, dis, csr, N);
    k_scan_add<<<nb_scan, 256, 0, stream>>>(off, csr, N);
    k_fill    <<<nb_E,    256, 0, stream>>>(src, dst, off, csr, E);

    // h0 = x @ W_in + b_in   (bf16-split output, in place; synced inside)
    k_mgemm<1><<<nb_mg, 256, 0, stream>>>(hh, hl, Wf, b_in, nullptr,
                                          nullptr, hh, hl, N);

    for (int layer = 0; layer < 3; ++layer) {
        const ushort* Wfm = Wf + (long long)(layer + 1) * 32768;
        const float* b = bs + (long long)layer * HDIM;
        // xwb = bf16( (h @ W) * dis[row] ), sliced layout
        k_mgemm<0><<<nb_mg, 256, 0, stream>>>(hh, hl, Wfm, nullptr, dis,
                                              xwb, nullptr, nullptr, N);
        if (layer == 2)
            k_agg<1><<<nb_agg, 256, 0, stream>>>(off, csr, dis, xwb, b,
                                                 (float*)d_out, nullptr, nullptr, N);
        else
            k_agg<0><<<nb_agg, 256, 0, stream>>>(off, csr, dis, xwb, b,
                                                 nullptr, hh, hl, N);
    }
}